// Round 1
// baseline (605.973 us; speedup 1.0000x reference)
//
#include <hip/hip_runtime.h>

// DeepGCN forward on MI355X.
// Structure: build CSR (by dest row) once per call, then
//   z = x@w1+b1 ; h = relu(A z)
//   L x: z = h@wm[i]+bm[i] ; h += relu(A z)*dt
//   z = h@w2+b2 ; out = A z
// CSR build avoids 82M fp32 atomics that a per-edge scatter-add would need.

#define DIN 256
#define HID 128
#define NCLS 64

// ---------------- CSR build ----------------

__global__ void hist_kernel(const int* __restrict__ row, int* __restrict__ deg, int E) {
    int e = blockIdx.x * blockDim.x + threadIdx.x;
    if (e < E) atomicAdd(&deg[row[e]], 1);
}

// Single-block exclusive scan over n ints (shuffle-based, ~2 barriers/tile).
__global__ void scan_kernel(const int* __restrict__ deg, int* __restrict__ offs, int n) {
    __shared__ int wsum[16];
    const int lane = threadIdx.x & 63;
    const int wid  = threadIdx.x >> 6;   // 0..15
    int carry = 0;
    for (int base = 0; base < n; base += 1024) {
        int i = base + (int)threadIdx.x;
        int v = (i < n) ? deg[i] : 0;
        int incl = v;
        #pragma unroll
        for (int d = 1; d < 64; d <<= 1) {
            int t = __shfl_up(incl, d, 64);
            if (lane >= d) incl += t;
        }
        if (lane == 63) wsum[wid] = incl;
        __syncthreads();
        int wprefix = 0, tile_total = 0;
        #pragma unroll
        for (int w = 0; w < 16; ++w) {
            int s = wsum[w];
            if (w < wid) wprefix += s;
            tile_total += s;
        }
        if (i < n) offs[i] = carry + wprefix + incl - v;   // exclusive
        __syncthreads();   // protect wsum before next tile's writes
        carry += tile_total;
    }
    if (threadIdx.x == 0) offs[n] = carry;
}

__global__ void fill_kernel(const int* __restrict__ row, const int* __restrict__ col,
                            const float* __restrict__ val, int* __restrict__ pos,
                            int* __restrict__ ccol, float* __restrict__ cval, int E) {
    int e = blockIdx.x * blockDim.x + threadIdx.x;
    if (e < E) {
        int r = row[e];
        int p = atomicAdd(&pos[r], 1);
        ccol[p] = col[e];
        cval[p] = val[e];
    }
}

// ---------------- dense GEMM + bias (fp32, 64x64 tile, BK=16) ----------------
// C[N,Hout] = A[N,K] @ W[K,Hout] + bias.  Requires N%64==0, Hout%64==0, K%16==0
// (holds here: N=40000=625*64, Hout in {128,64}, K in {256,128}).
__global__ __launch_bounds__(256) void gemm_bias_kernel(
        const float* __restrict__ A, const float* __restrict__ W,
        const float* __restrict__ bias, float* __restrict__ C, int K, int Hout) {
    __shared__ float As[16][65];   // transposed A tile: As[k][m], pad breaks bank stride
    __shared__ float Ws[16][65];   // Ws[k][n]
    const int bm = blockIdx.x * 64;
    const int bn = blockIdx.y * 64;
    const int tid = threadIdx.x;
    const int tm = (tid >> 4) << 2;   // 0..60
    const int tn = (tid & 15) << 2;   // 0..60
    const int arow = tid >> 2;        // 0..63
    const int akq  = (tid & 3) << 2;  // 0,4,8,12
    const int wk   = tid >> 4;        // 0..15
    const int wj   = (tid & 15) << 2; // 0..60

    float acc[4][4] = {};
    for (int k0 = 0; k0 < K; k0 += 16) {
        float4 av = *(const float4*)&A[(size_t)(bm + arow) * K + k0 + akq];
        float4 wv = *(const float4*)&W[(size_t)(k0 + wk) * Hout + bn + wj];
        As[akq + 0][arow] = av.x;
        As[akq + 1][arow] = av.y;
        As[akq + 2][arow] = av.z;
        As[akq + 3][arow] = av.w;
        Ws[wk][wj + 0] = wv.x;
        Ws[wk][wj + 1] = wv.y;
        Ws[wk][wj + 2] = wv.z;
        Ws[wk][wj + 3] = wv.w;
        __syncthreads();
        #pragma unroll
        for (int k = 0; k < 16; ++k) {
            float a0 = As[k][tm + 0], a1 = As[k][tm + 1];
            float a2 = As[k][tm + 2], a3 = As[k][tm + 3];
            float b0 = Ws[k][tn + 0], b1 = Ws[k][tn + 1];
            float b2 = Ws[k][tn + 2], b3 = Ws[k][tn + 3];
            acc[0][0] += a0 * b0; acc[0][1] += a0 * b1; acc[0][2] += a0 * b2; acc[0][3] += a0 * b3;
            acc[1][0] += a1 * b0; acc[1][1] += a1 * b1; acc[1][2] += a1 * b2; acc[1][3] += a1 * b3;
            acc[2][0] += a2 * b0; acc[2][1] += a2 * b1; acc[2][2] += a2 * b2; acc[2][3] += a2 * b3;
            acc[3][0] += a3 * b0; acc[3][1] += a3 * b1; acc[3][2] += a3 * b2; acc[3][3] += a3 * b3;
        }
        __syncthreads();
    }
    float bb0 = bias[bn + tn + 0], bb1 = bias[bn + tn + 1];
    float bb2 = bias[bn + tn + 2], bb3 = bias[bn + tn + 3];
    #pragma unroll
    for (int i = 0; i < 4; ++i) {
        float4 o;
        o.x = acc[i][0] + bb0;
        o.y = acc[i][1] + bb1;
        o.z = acc[i][2] + bb2;
        o.w = acc[i][3] + bb3;
        *(float4*)&C[(size_t)(bm + tm + i) * Hout + bn + tn] = o;
    }
}

// ---------------- SpMM: out[r,:] = sum_{e in row r} val[e]*z[col[e],:] ------
// One wave per output row (avg degree 16). col/val are wave-uniform loads
// (compiler scalarizes); z row gathers are 256B coalesced per load.
// MODE 0: out = relu(s)      MODE 1: out += relu(s)*dt      MODE 2: out = s
template <int D, int MODE>
__global__ __launch_bounds__(256) void spmm_kernel(
        const int* __restrict__ offs, const int* __restrict__ ccol,
        const float* __restrict__ cval, const float* __restrict__ z,
        float* __restrict__ out, const float* __restrict__ dt_ptr, int n) {
    int r = (int)((blockIdx.x * blockDim.x + threadIdx.x) >> 6);
    int lane = threadIdx.x & 63;
    if (r >= n) return;
    int s = offs[r], e = offs[r + 1];
    float acc0 = 0.f, acc1 = 0.f;
    for (int p = s; p < e; ++p) {
        int   c = ccol[p];
        float v = cval[p];
        const float* zr = z + (size_t)c * D;
        acc0 = fmaf(v, zr[lane], acc0);
        if (D == 128) acc1 = fmaf(v, zr[lane + 64], acc1);
    }
    size_t o = (size_t)r * D + lane;
    if (MODE == 0) {
        out[o] = fmaxf(acc0, 0.f);
        if (D == 128) out[o + 64] = fmaxf(acc1, 0.f);
    } else if (MODE == 1) {
        float dt = *dt_ptr;
        out[o] += fmaxf(acc0, 0.f) * dt;
        if (D == 128) out[o + 64] += fmaxf(acc1, 0.f) * dt;
    } else {
        out[o] = acc0;
        if (D == 128) out[o + 64] = acc1;
    }
}

extern "C" void kernel_launch(void* const* d_in, const int* in_sizes, int n_in,
                              void* d_out, int out_size, void* d_ws, size_t ws_size,
                              hipStream_t stream) {
    const float* x    = (const float*)d_in[0];
    const int*   erow = (const int*)d_in[1];
    const int*   ecol = (const int*)d_in[2];
    const float* eval = (const float*)d_in[3];
    const float* w1   = (const float*)d_in[4];
    const float* b1   = (const float*)d_in[5];
    const float* wm   = (const float*)d_in[6];
    const float* bmp  = (const float*)d_in[7];
    const float* w2   = (const float*)d_in[8];
    const float* b2   = (const float*)d_in[9];
    const float* dt   = (const float*)d_in[10];

    const int N = in_sizes[0] / DIN;       // 40000
    const int E = in_sizes[1];             // 640000
    const int L = in_sizes[7] / HID;       // 2

    float* outp = (float*)d_out;

    // workspace carving (256B aligned): ~46.5 MB total
    char* ws = (char*)d_ws;
    auto carve = [&](size_t bytes) -> char* {
        char* p = ws;
        ws += (bytes + 255) & ~(size_t)255;
        return p;
    };
    int*   deg  = (int*)carve((size_t)N * 4);
    int*   offs = (int*)carve((size_t)(N + 1) * 4);
    int*   pos  = (int*)carve((size_t)N * 4);
    int*   ccol = (int*)carve((size_t)E * 4);
    float* cval = (float*)carve((size_t)E * 4);
    float* z    = (float*)carve((size_t)N * HID * 4);
    float* h    = (float*)carve((size_t)N * HID * 4);

    // --- CSR build ---
    hipMemsetAsync(deg, 0, (size_t)N * 4, stream);
    hist_kernel<<<(E + 255) / 256, 256, 0, stream>>>(erow, deg, E);
    scan_kernel<<<1, 1024, 0, stream>>>(deg, offs, N);
    hipMemcpyAsync(pos, offs, (size_t)N * 4, hipMemcpyDeviceToDevice, stream);
    fill_kernel<<<(E + 255) / 256, 256, 0, stream>>>(erow, ecol, eval, pos, ccol, cval, E);

    const int spmm_blocks = (N + 3) / 4;   // 4 waves (rows) per 256-thread block

    // --- layer 1 ---
    gemm_bias_kernel<<<dim3(N / 64, HID / 64), 256, 0, stream>>>(x, w1, b1, z, DIN, HID);
    spmm_kernel<HID, 0><<<spmm_blocks, 256, 0, stream>>>(offs, ccol, cval, z, h, nullptr, N);

    // --- middle residual layers ---
    for (int i = 0; i < L; ++i) {
        gemm_bias_kernel<<<dim3(N / 64, HID / 64), 256, 0, stream>>>(
            h, wm + (size_t)i * HID * HID, bmp + (size_t)i * HID, z, HID, HID);
        spmm_kernel<HID, 1><<<spmm_blocks, 256, 0, stream>>>(offs, ccol, cval, z, h, dt, N);
    }

    // --- output layer ---
    gemm_bias_kernel<<<dim3(N / 64, NCLS / 64), 256, 0, stream>>>(h, w2, b2, z, HID, NCLS);
    spmm_kernel<NCLS, 2><<<spmm_blocks, 256, 0, stream>>>(offs, ccol, cval, z, outp, nullptr, N);
}

// Round 2
// 427.374 us; speedup vs baseline: 1.4179x; 1.4179x over previous
//
#include <hip/hip_runtime.h>

// DeepGCN forward on MI355X.
// CSR build once per call (avoids 82M fp32 atomics), then GEMM -> SpMM x4.
// Activations staged to the SpMM (z) are bf16: halves gather bytes and
// doubles effective L2 coverage (SpMM was L2-miss-path bound: 146MB FETCH
// @2.4TB/s, VALUBusy 13%). Accumulation everywhere is fp32.

#define DIN 256
#define HID 128
#define NCLS 64

static __device__ __forceinline__ float bf2f(unsigned int u) {
    return __uint_as_float(u << 16);
}
static __device__ __forceinline__ unsigned short f2bf(float f) {
    unsigned int i = __float_as_uint(f);
    unsigned int r = (i + 0x7FFFu + ((i >> 16) & 1u)) >> 16;   // RNE
    return (unsigned short)r;
}

// ---------------- CSR build ----------------

__global__ void hist_kernel(const int* __restrict__ row, int* __restrict__ deg, int E) {
    int e = blockIdx.x * blockDim.x + threadIdx.x;
    if (e < E) atomicAdd(&deg[row[e]], 1);
}

__global__ void scan_kernel(const int* __restrict__ deg, int* __restrict__ offs, int n) {
    __shared__ int wsum[16];
    const int lane = threadIdx.x & 63;
    const int wid  = threadIdx.x >> 6;
    int carry = 0;
    for (int base = 0; base < n; base += 1024) {
        int i = base + (int)threadIdx.x;
        int v = (i < n) ? deg[i] : 0;
        int incl = v;
        #pragma unroll
        for (int d = 1; d < 64; d <<= 1) {
            int t = __shfl_up(incl, d, 64);
            if (lane >= d) incl += t;
        }
        if (lane == 63) wsum[wid] = incl;
        __syncthreads();
        int wprefix = 0, tile_total = 0;
        #pragma unroll
        for (int w = 0; w < 16; ++w) {
            int s = wsum[w];
            if (w < wid) wprefix += s;
            tile_total += s;
        }
        if (i < n) offs[i] = carry + wprefix + incl - v;
        __syncthreads();
        carry += tile_total;
    }
    if (threadIdx.x == 0) offs[n] = carry;
}

__global__ void fill_kernel(const int* __restrict__ row, const int* __restrict__ col,
                            const float* __restrict__ val, int* __restrict__ pos,
                            int* __restrict__ ccol, float* __restrict__ cval, int E) {
    int e = blockIdx.x * blockDim.x + threadIdx.x;
    if (e < E) {
        int r = row[e];
        int p = atomicAdd(&pos[r], 1);
        ccol[p] = col[e];
        cval[p] = val[e];
    }
}

// ------------- GEMM 128x128 tile, fp32 in, bf16 out, Hout=128 fixed -------------
// 256 threads, 8x8/thread as split groups {tm..tm+3, tm+64..tm+67} x {tn..,tn+64..}
// so LDS reads are 2-way-bank-aliased float4s (free). M-edge: clamp load, guard store.
__global__ __launch_bounds__(256) void gemm128_kernel(
        const float* __restrict__ A, const float* __restrict__ W,
        const float* __restrict__ bias, unsigned short* __restrict__ C,
        int N, int K) {
    __shared__ float As[16][132];
    __shared__ float Ws[16][132];
    const int bm = blockIdx.x * 128;
    const int tid = threadIdx.x;
    const int tm = (tid >> 4) * 4;
    const int tn = (tid & 15) * 4;
    const int arow = tid >> 1;
    const int acol = (tid & 1) * 8;
    const int wrow = tid >> 4;
    const int wcol = (tid & 15) * 8;
    const int arow_g = min(bm + arow, N - 1);

    float acc[8][8] = {};
    for (int k0 = 0; k0 < K; k0 += 16) {
        float4 a0 = *(const float4*)&A[(size_t)arow_g * K + k0 + acol];
        float4 a1 = *(const float4*)&A[(size_t)arow_g * K + k0 + acol + 4];
        float4 w0 = *(const float4*)&W[(size_t)(k0 + wrow) * 128 + wcol];
        float4 w1 = *(const float4*)&W[(size_t)(k0 + wrow) * 128 + wcol + 4];
        As[acol + 0][arow] = a0.x; As[acol + 1][arow] = a0.y;
        As[acol + 2][arow] = a0.z; As[acol + 3][arow] = a0.w;
        As[acol + 4][arow] = a1.x; As[acol + 5][arow] = a1.y;
        As[acol + 6][arow] = a1.z; As[acol + 7][arow] = a1.w;
        *(float4*)&Ws[wrow][wcol]     = w0;
        *(float4*)&Ws[wrow][wcol + 4] = w1;
        __syncthreads();
        #pragma unroll
        for (int k = 0; k < 16; ++k) {
            float ar[8], wr[8];
            *(float4*)&ar[0] = *(const float4*)&As[k][tm];
            *(float4*)&ar[4] = *(const float4*)&As[k][tm + 64];
            *(float4*)&wr[0] = *(const float4*)&Ws[k][tn];
            *(float4*)&wr[4] = *(const float4*)&Ws[k][tn + 64];
            #pragma unroll
            for (int i = 0; i < 8; ++i)
                #pragma unroll
                for (int j = 0; j < 8; ++j)
                    acc[i][j] = fmaf(ar[i], wr[j], acc[i][j]);
        }
        __syncthreads();
    }
    float bb[8];
    #pragma unroll
    for (int j = 0; j < 4; ++j) {
        bb[j]     = bias[tn + j];
        bb[j + 4] = bias[tn + 64 + j];
    }
    #pragma unroll
    for (int i = 0; i < 8; ++i) {
        int row = bm + tm + (i < 4 ? i : 60 + i);
        if (row < N) {
            ushort4 o;
            o.x = f2bf(acc[i][0] + bb[0]); o.y = f2bf(acc[i][1] + bb[1]);
            o.z = f2bf(acc[i][2] + bb[2]); o.w = f2bf(acc[i][3] + bb[3]);
            *(ushort4*)&C[(size_t)row * 128 + tn] = o;
            ushort4 o2;
            o2.x = f2bf(acc[i][4] + bb[4]); o2.y = f2bf(acc[i][5] + bb[5]);
            o2.z = f2bf(acc[i][6] + bb[6]); o2.w = f2bf(acc[i][7] + bb[7]);
            *(ushort4*)&C[(size_t)row * 128 + tn + 64] = o2;
        }
    }
}

// ------------- GEMM 64x64 tile, fp32 in, bf16 out (for Hout=64) -------------
__global__ __launch_bounds__(256) void gemm64_kernel(
        const float* __restrict__ A, const float* __restrict__ W,
        const float* __restrict__ bias, unsigned short* __restrict__ C,
        int K, int Hout) {
    __shared__ float As[16][65];
    __shared__ float Ws[16][65];
    const int bm = blockIdx.x * 64;
    const int bn = blockIdx.y * 64;
    const int tid = threadIdx.x;
    const int tm = (tid >> 4) << 2;
    const int tn = (tid & 15) << 2;
    const int arow = tid >> 2;
    const int akq  = (tid & 3) << 2;
    const int wk   = tid >> 4;
    const int wj   = (tid & 15) << 2;

    float acc[4][4] = {};
    for (int k0 = 0; k0 < K; k0 += 16) {
        float4 av = *(const float4*)&A[(size_t)(bm + arow) * K + k0 + akq];
        float4 wv = *(const float4*)&W[(size_t)(k0 + wk) * Hout + bn + wj];
        As[akq + 0][arow] = av.x; As[akq + 1][arow] = av.y;
        As[akq + 2][arow] = av.z; As[akq + 3][arow] = av.w;
        Ws[wk][wj + 0] = wv.x; Ws[wk][wj + 1] = wv.y;
        Ws[wk][wj + 2] = wv.z; Ws[wk][wj + 3] = wv.w;
        __syncthreads();
        #pragma unroll
        for (int k = 0; k < 16; ++k) {
            float a0 = As[k][tm + 0], a1 = As[k][tm + 1];
            float a2 = As[k][tm + 2], a3 = As[k][tm + 3];
            float b0 = Ws[k][tn + 0], b1 = Ws[k][tn + 1];
            float b2 = Ws[k][tn + 2], b3 = Ws[k][tn + 3];
            acc[0][0] = fmaf(a0, b0, acc[0][0]); acc[0][1] = fmaf(a0, b1, acc[0][1]);
            acc[0][2] = fmaf(a0, b2, acc[0][2]); acc[0][3] = fmaf(a0, b3, acc[0][3]);
            acc[1][0] = fmaf(a1, b0, acc[1][0]); acc[1][1] = fmaf(a1, b1, acc[1][1]);
            acc[1][2] = fmaf(a1, b2, acc[1][2]); acc[1][3] = fmaf(a1, b3, acc[1][3]);
            acc[2][0] = fmaf(a2, b0, acc[2][0]); acc[2][1] = fmaf(a2, b1, acc[2][1]);
            acc[2][2] = fmaf(a2, b2, acc[2][2]); acc[2][3] = fmaf(a2, b3, acc[2][3]);
            acc[3][0] = fmaf(a3, b0, acc[3][0]); acc[3][1] = fmaf(a3, b1, acc[3][1]);
            acc[3][2] = fmaf(a3, b2, acc[3][2]); acc[3][3] = fmaf(a3, b3, acc[3][3]);
        }
        __syncthreads();
    }
    float bb0 = bias[bn + tn + 0], bb1 = bias[bn + tn + 1];
    float bb2 = bias[bn + tn + 2], bb3 = bias[bn + tn + 3];
    #pragma unroll
    for (int i = 0; i < 4; ++i) {
        ushort4 o;
        o.x = f2bf(acc[i][0] + bb0); o.y = f2bf(acc[i][1] + bb1);
        o.z = f2bf(acc[i][2] + bb2); o.w = f2bf(acc[i][3] + bb3);
        *(ushort4*)&C[(size_t)(bm + tm + i) * Hout + bn + tn] = o;
    }
}

// ---------------- SpMM over bf16 z, fp32 accumulate ----------------
// One wave per row; edge loop unrolled x4 for gather MLP; col/val scalarized.
// MODE 0: out = relu(s)   MODE 1: out += relu(s)*dt   MODE 2: out = s
template <int D, int MODE>
__global__ __launch_bounds__(256) void spmm_kernel(
        const int* __restrict__ offs, const int* __restrict__ ccol,
        const float* __restrict__ cval, const unsigned short* __restrict__ z,
        float* __restrict__ out, const float* __restrict__ dt_ptr, int n) {
    int r = (int)((blockIdx.x * blockDim.x + threadIdx.x) >> 6);
    int lane = threadIdx.x & 63;
    if (r >= n) return;
    r = __builtin_amdgcn_readfirstlane(r);   // wave-uniform: scalarize CSR loads
    const int s = offs[r], e = offs[r + 1];
    float acc0 = 0.f, acc1 = 0.f;
    int p = s;
    if (D == 128) {
        const unsigned int* z32 = (const unsigned int*)z;
        for (; p + 4 <= e; p += 4) {
            int c0 = ccol[p], c1 = ccol[p + 1], c2 = ccol[p + 2], c3 = ccol[p + 3];
            float v0 = cval[p], v1 = cval[p + 1], v2 = cval[p + 2], v3 = cval[p + 3];
            unsigned int g0 = z32[(size_t)c0 * 64 + lane];
            unsigned int g1 = z32[(size_t)c1 * 64 + lane];
            unsigned int g2 = z32[(size_t)c2 * 64 + lane];
            unsigned int g3 = z32[(size_t)c3 * 64 + lane];
            acc0 = fmaf(v0, bf2f(g0 & 0xffffu), acc0); acc1 = fmaf(v0, bf2f(g0 >> 16), acc1);
            acc0 = fmaf(v1, bf2f(g1 & 0xffffu), acc0); acc1 = fmaf(v1, bf2f(g1 >> 16), acc1);
            acc0 = fmaf(v2, bf2f(g2 & 0xffffu), acc0); acc1 = fmaf(v2, bf2f(g2 >> 16), acc1);
            acc0 = fmaf(v3, bf2f(g3 & 0xffffu), acc0); acc1 = fmaf(v3, bf2f(g3 >> 16), acc1);
        }
        for (; p < e; ++p) {
            float v = cval[p];
            unsigned int g = z32[(size_t)ccol[p] * 64 + lane];
            acc0 = fmaf(v, bf2f(g & 0xffffu), acc0); acc1 = fmaf(v, bf2f(g >> 16), acc1);
        }
        // lane holds cols {2*lane, 2*lane+1}
        float2* op = (float2*)&out[(size_t)r * 128 + 2 * lane];
        if (MODE == 0) {
            float2 o; o.x = fmaxf(acc0, 0.f); o.y = fmaxf(acc1, 0.f);
            *op = o;
        } else if (MODE == 1) {
            float dt = *dt_ptr;
            float2 cur = *op;
            cur.x += fmaxf(acc0, 0.f) * dt;
            cur.y += fmaxf(acc1, 0.f) * dt;
            *op = cur;
        } else {
            float2 o; o.x = acc0; o.y = acc1;
            *op = o;
        }
    } else {  // D == 64
        for (; p + 4 <= e; p += 4) {
            int c0 = ccol[p], c1 = ccol[p + 1], c2 = ccol[p + 2], c3 = ccol[p + 3];
            float v0 = cval[p], v1 = cval[p + 1], v2 = cval[p + 2], v3 = cval[p + 3];
            unsigned int g0 = z[(size_t)c0 * 64 + lane];
            unsigned int g1 = z[(size_t)c1 * 64 + lane];
            unsigned int g2 = z[(size_t)c2 * 64 + lane];
            unsigned int g3 = z[(size_t)c3 * 64 + lane];
            acc0 = fmaf(v0, bf2f(g0), acc0);
            acc0 = fmaf(v1, bf2f(g1), acc0);
            acc0 = fmaf(v2, bf2f(g2), acc0);
            acc0 = fmaf(v3, bf2f(g3), acc0);
        }
        for (; p < e; ++p)
            acc0 = fmaf(cval[p], bf2f((unsigned int)z[(size_t)ccol[p] * 64 + lane]), acc0);
        size_t o = (size_t)r * 64 + lane;
        if (MODE == 2) out[o] = acc0;
        else if (MODE == 0) out[o] = fmaxf(acc0, 0.f);
        else out[o] += fmaxf(acc0, 0.f) * (*dt_ptr);
    }
}

extern "C" void kernel_launch(void* const* d_in, const int* in_sizes, int n_in,
                              void* d_out, int out_size, void* d_ws, size_t ws_size,
                              hipStream_t stream) {
    const float* x    = (const float*)d_in[0];
    const int*   erow = (const int*)d_in[1];
    const int*   ecol = (const int*)d_in[2];
    const float* eval = (const float*)d_in[3];
    const float* w1   = (const float*)d_in[4];
    const float* b1   = (const float*)d_in[5];
    const float* wm   = (const float*)d_in[6];
    const float* bmp  = (const float*)d_in[7];
    const float* w2   = (const float*)d_in[8];
    const float* b2   = (const float*)d_in[9];
    const float* dt   = (const float*)d_in[10];

    const int N = in_sizes[0] / DIN;       // 40000
    const int E = in_sizes[1];             // 640000
    const int L = in_sizes[7] / HID;       // 2

    float* outp = (float*)d_out;

    char* ws = (char*)d_ws;
    auto carve = [&](size_t bytes) -> char* {
        char* p = ws;
        ws += (bytes + 255) & ~(size_t)255;
        return p;
    };
    int*            deg  = (int*)carve((size_t)N * 4);
    int*            offs = (int*)carve((size_t)(N + 1) * 4);
    int*            pos  = (int*)carve((size_t)N * 4);
    int*            ccol = (int*)carve((size_t)E * 4);
    float*          cval = (float*)carve((size_t)E * 4);
    unsigned short* z    = (unsigned short*)carve((size_t)N * HID * 2);  // bf16
    float*          h    = (float*)carve((size_t)N * HID * 4);

    // --- CSR build ---
    hipMemsetAsync(deg, 0, (size_t)N * 4, stream);
    hist_kernel<<<(E + 255) / 256, 256, 0, stream>>>(erow, deg, E);
    scan_kernel<<<1, 1024, 0, stream>>>(deg, offs, N);
    hipMemcpyAsync(pos, offs, (size_t)N * 4, hipMemcpyDeviceToDevice, stream);
    fill_kernel<<<(E + 255) / 256, 256, 0, stream>>>(erow, ecol, eval, pos, ccol, cval, E);

    const int spmm_blocks = (N + 3) / 4;
    const int gemm128_blocks = (N + 127) / 128;

    // --- layer 1 ---
    gemm128_kernel<<<gemm128_blocks, 256, 0, stream>>>(x, w1, b1, z, N, DIN);
    spmm_kernel<HID, 0><<<spmm_blocks, 256, 0, stream>>>(offs, ccol, cval, z, h, nullptr, N);

    // --- middle residual layers ---
    for (int i = 0; i < L; ++i) {
        gemm128_kernel<<<gemm128_blocks, 256, 0, stream>>>(
            h, wm + (size_t)i * HID * HID, bmp + (size_t)i * HID, z, N, HID);
        spmm_kernel<HID, 1><<<spmm_blocks, 256, 0, stream>>>(offs, ccol, cval, z, h, dt, N);
    }

    // --- output layer ---
    gemm64_kernel<<<dim3(N / 64, NCLS / 64), 256, 0, stream>>>(h, w2, b2, z, HID, NCLS);
    spmm_kernel<NCLS, 2><<<spmm_blocks, 256, 0, stream>>>(offs, ccol, cval, z, outp, nullptr, N);
}

// Round 3
// 362.899 us; speedup vs baseline: 1.6698x; 1.1777x over previous
//
#include <hip/hip_runtime.h>

// DeepGCN forward on MI355X.
// CSR build once per call; GEMMs via MFMA bf16 (16x16x32), activations staged
// bf16 (z for SpMM gather, hb for GEMM A); fp32 h kept for exact-ish residual.
// R2 post-mortem: fp32 VALU GEMM was latency-bound (occ 10%, VALUBusy 26%,
// 68us/dispatch). MFMA + 625-block grid attacks that directly.

#define DIN 256
#define HID 128
#define NCLS 64

typedef __attribute__((ext_vector_type(8))) short bf16x8;   // 8 bf16 = 4 VGPRs
typedef __attribute__((ext_vector_type(4))) float f32x4;

static __device__ __forceinline__ float bf2f(unsigned int u) {
    return __uint_as_float(u << 16);
}
static __device__ __forceinline__ unsigned short f2bf(float f) {
    unsigned int i = __float_as_uint(f);
    unsigned int r = (i + 0x7FFFu + ((i >> 16) & 1u)) >> 16;   // RNE
    return (unsigned short)r;
}

// ---------------- CSR build ----------------

__global__ void hist_kernel(const int* __restrict__ row, int* __restrict__ deg, int E) {
    int e = blockIdx.x * blockDim.x + threadIdx.x;
    if (e < E) atomicAdd(&deg[row[e]], 1);
}

__global__ void scan_kernel(const int* __restrict__ deg, int* __restrict__ offs, int n) {
    __shared__ int wsum[16];
    const int lane = threadIdx.x & 63;
    const int wid  = threadIdx.x >> 6;
    int carry = 0;
    for (int base = 0; base < n; base += 1024) {
        int i = base + (int)threadIdx.x;
        int v = (i < n) ? deg[i] : 0;
        int incl = v;
        #pragma unroll
        for (int d = 1; d < 64; d <<= 1) {
            int t = __shfl_up(incl, d, 64);
            if (lane >= d) incl += t;
        }
        if (lane == 63) wsum[wid] = incl;
        __syncthreads();
        int wprefix = 0, tile_total = 0;
        #pragma unroll
        for (int w = 0; w < 16; ++w) {
            int s = wsum[w];
            if (w < wid) wprefix += s;
            tile_total += s;
        }
        if (i < n) offs[i] = carry + wprefix + incl - v;
        __syncthreads();
        carry += tile_total;
    }
    if (threadIdx.x == 0) offs[n] = carry;
}

__global__ void fill_kernel(const int* __restrict__ row, const int* __restrict__ col,
                            const float* __restrict__ val, int* __restrict__ pos,
                            int* __restrict__ ccol, float* __restrict__ cval, int E) {
    int e = blockIdx.x * blockDim.x + threadIdx.x;
    if (e < E) {
        int r = row[e];
        int p = atomicAdd(&pos[r], 1);
        ccol[p] = col[e];
        cval[p] = val[e];
    }
}

// ---------------- preprocessing ----------------

__global__ void f2bf_vec_kernel(const float* __restrict__ in, unsigned short* __restrict__ out, int n4) {
    int i = blockIdx.x * blockDim.x + threadIdx.x;
    if (i < n4) {
        float4 v = *(const float4*)&in[i * 4];
        ushort4 o;
        o.x = f2bf(v.x); o.y = f2bf(v.y); o.z = f2bf(v.z); o.w = f2bf(v.w);
        *(ushort4*)&out[i * 4] = o;
    }
}

// out[n*K + k] = bf16(in[k*Hout + n])  -- weights are tiny, simple is fine
__global__ void wtrans_kernel(const float* __restrict__ in, unsigned short* __restrict__ out,
                              int K, int Hout) {
    int idx = blockIdx.x * blockDim.x + threadIdx.x;
    if (idx < K * Hout) {
        int n = idx / K, k = idx - n * K;
        out[idx] = f2bf(in[(size_t)k * Hout + n]);
    }
}

// ---------------- MFMA bf16 GEMM:  C[N,BN] = A[N,K] @ Wt[BN,K]^T + bias ----------------
// 256 threads = 4 waves; block tile 64 x BN; wave w does rows w*16..w*16+15.
// LDS rows padded to stride 40 bf16 (80 B): ds_read_b128 frags are 2-way bank
// aliased (free, m136). Grid = N/64 = 625 exact (40000 % 64 == 0).
template <int BN>
__global__ __launch_bounds__(256) void gemm_mfma_kernel(
        const unsigned short* __restrict__ A, const unsigned short* __restrict__ Wt,
        const float* __restrict__ bias, unsigned short* __restrict__ C, int K) {
    constexpr int NT = BN / 16;                       // MFMA tiles per wave
    __shared__ __align__(16) unsigned short Alds[64 * 40];
    __shared__ __align__(16) unsigned short Blds[BN * 40];
    const int tid  = threadIdx.x;
    const int bm   = blockIdx.x * 64;
    const int wave = tid >> 6;
    const int lane = tid & 63;
    const int m16  = lane & 15;
    const int quad = lane >> 4;
    const int ar = tid >> 2, ac = (tid & 3) * 8;      // A staging: 64 rows x 4 chunks

    f32x4 acc[NT] = {};
    for (int k0 = 0; k0 < K; k0 += 32) {
        uint4 av = *(const uint4*)&A[(size_t)(bm + ar) * K + k0 + ac];
        *(uint4*)&Alds[ar * 40 + ac] = av;
        #pragma unroll
        for (int i = 0; i < BN / 64; ++i) {
            int c  = tid + 256 * i;
            int br = c >> 2, bc = (c & 3) * 8;
            uint4 bv = *(const uint4*)&Wt[(size_t)br * K + k0 + bc];
            *(uint4*)&Blds[br * 40 + bc] = bv;
        }
        __syncthreads();
        bf16x8 af = *(const bf16x8*)&Alds[(wave * 16 + m16) * 40 + quad * 8];
        #pragma unroll
        for (int j = 0; j < NT; ++j) {
            bf16x8 bf = *(const bf16x8*)&Blds[(j * 16 + m16) * 40 + quad * 8];
            acc[j] = __builtin_amdgcn_mfma_f32_16x16x32_bf16(af, bf, acc[j], 0, 0, 0);
        }
        __syncthreads();
    }
    // C/D layout: col = lane&15, row = quad*4 + reg  (m89-verified)
    #pragma unroll
    for (int j = 0; j < NT; ++j) {
        int col = j * 16 + m16;
        float bb = bias[col];
        #pragma unroll
        for (int r = 0; r < 4; ++r) {
            int row = bm + wave * 16 + quad * 4 + r;
            C[(size_t)row * BN + col] = f2bf(acc[j][r] + bb);
        }
    }
}

// ---------------- SpMM over bf16 z, fp32 accumulate ----------------
// One wave per row; x4 unroll; wave-uniform CSR loads.
// MODE 0: h = relu(s); hb = bf16(h)
// MODE 1: h += relu(s)*dt; hb = bf16(h)
// MODE 2: out = s (fp32, no hb)
template <int D, int MODE>
__global__ __launch_bounds__(256) void spmm_kernel(
        const int* __restrict__ offs, const int* __restrict__ ccol,
        const float* __restrict__ cval, const unsigned short* __restrict__ z,
        float* __restrict__ out, unsigned short* __restrict__ hb,
        const float* __restrict__ dt_ptr, int n) {
    int r = (int)((blockIdx.x * blockDim.x + threadIdx.x) >> 6);
    int lane = threadIdx.x & 63;
    if (r >= n) return;
    r = __builtin_amdgcn_readfirstlane(r);
    const int s = offs[r], e = offs[r + 1];
    float acc0 = 0.f, acc1 = 0.f;
    int p = s;
    if (D == 128) {
        const unsigned int* z32 = (const unsigned int*)z;
        for (; p + 4 <= e; p += 4) {
            int c0 = ccol[p], c1 = ccol[p + 1], c2 = ccol[p + 2], c3 = ccol[p + 3];
            float v0 = cval[p], v1 = cval[p + 1], v2 = cval[p + 2], v3 = cval[p + 3];
            unsigned int g0 = z32[(size_t)c0 * 64 + lane];
            unsigned int g1 = z32[(size_t)c1 * 64 + lane];
            unsigned int g2 = z32[(size_t)c2 * 64 + lane];
            unsigned int g3 = z32[(size_t)c3 * 64 + lane];
            acc0 = fmaf(v0, bf2f(g0 & 0xffffu), acc0); acc1 = fmaf(v0, bf2f(g0 >> 16), acc1);
            acc0 = fmaf(v1, bf2f(g1 & 0xffffu), acc0); acc1 = fmaf(v1, bf2f(g1 >> 16), acc1);
            acc0 = fmaf(v2, bf2f(g2 & 0xffffu), acc0); acc1 = fmaf(v2, bf2f(g2 >> 16), acc1);
            acc0 = fmaf(v3, bf2f(g3 & 0xffffu), acc0); acc1 = fmaf(v3, bf2f(g3 >> 16), acc1);
        }
        for (; p < e; ++p) {
            float v = cval[p];
            unsigned int g = z32[(size_t)ccol[p] * 64 + lane];
            acc0 = fmaf(v, bf2f(g & 0xffffu), acc0); acc1 = fmaf(v, bf2f(g >> 16), acc1);
        }
        // lane holds cols {2*lane, 2*lane+1}
        float2* op = (float2*)&out[(size_t)r * 128 + 2 * lane];
        float f0, f1;
        if (MODE == 0) {
            f0 = fmaxf(acc0, 0.f); f1 = fmaxf(acc1, 0.f);
            float2 o; o.x = f0; o.y = f1; *op = o;
        } else if (MODE == 1) {
            float dt = *dt_ptr;
            float2 cur = *op;
            f0 = cur.x + fmaxf(acc0, 0.f) * dt;
            f1 = cur.y + fmaxf(acc1, 0.f) * dt;
            float2 o; o.x = f0; o.y = f1; *op = o;
        } else {
            float2 o; o.x = acc0; o.y = acc1; *op = o;
            return;
        }
        unsigned int packed = (unsigned int)f2bf(f0) | ((unsigned int)f2bf(f1) << 16);
        ((unsigned int*)hb)[(size_t)r * 64 + lane] = packed;
    } else {  // D == 64 (final layer, MODE 2 only)
        for (; p + 4 <= e; p += 4) {
            int c0 = ccol[p], c1 = ccol[p + 1], c2 = ccol[p + 2], c3 = ccol[p + 3];
            float v0 = cval[p], v1 = cval[p + 1], v2 = cval[p + 2], v3 = cval[p + 3];
            acc0 = fmaf(v0, bf2f((unsigned int)z[(size_t)c0 * 64 + lane]), acc0);
            acc0 = fmaf(v1, bf2f((unsigned int)z[(size_t)c1 * 64 + lane]), acc0);
            acc0 = fmaf(v2, bf2f((unsigned int)z[(size_t)c2 * 64 + lane]), acc0);
            acc0 = fmaf(v3, bf2f((unsigned int)z[(size_t)c3 * 64 + lane]), acc0);
        }
        for (; p < e; ++p)
            acc0 = fmaf(cval[p], bf2f((unsigned int)z[(size_t)ccol[p] * 64 + lane]), acc0);
        out[(size_t)r * 64 + lane] = acc0;
    }
}

extern "C" void kernel_launch(void* const* d_in, const int* in_sizes, int n_in,
                              void* d_out, int out_size, void* d_ws, size_t ws_size,
                              hipStream_t stream) {
    const float* x    = (const float*)d_in[0];
    const int*   erow = (const int*)d_in[1];
    const int*   ecol = (const int*)d_in[2];
    const float* eval = (const float*)d_in[3];
    const float* w1   = (const float*)d_in[4];
    const float* b1   = (const float*)d_in[5];
    const float* wm   = (const float*)d_in[6];
    const float* bmp  = (const float*)d_in[7];
    const float* w2   = (const float*)d_in[8];
    const float* b2   = (const float*)d_in[9];
    const float* dt   = (const float*)d_in[10];

    const int N = in_sizes[0] / DIN;       // 40000
    const int E = in_sizes[1];             // 640000
    const int L = in_sizes[7] / HID;       // 2

    float* outp = (float*)d_out;

    char* ws = (char*)d_ws;
    auto carve = [&](size_t bytes) -> char* {
        char* p = ws;
        ws += (bytes + 255) & ~(size_t)255;
        return p;
    };
    int*            deg  = (int*)carve((size_t)N * 4);
    int*            offs = (int*)carve((size_t)(N + 1) * 4);
    int*            pos  = (int*)carve((size_t)N * 4);
    int*            ccol = (int*)carve((size_t)E * 4);
    float*          cval = (float*)carve((size_t)E * 4);
    unsigned short* z    = (unsigned short*)carve((size_t)N * HID * 2);   // bf16 gather matrix
    float*          h    = (float*)carve((size_t)N * HID * 4);            // fp32 residual state
    unsigned short* xb   = (unsigned short*)carve((size_t)N * DIN * 2);   // bf16 x; reused as hb
    unsigned short* w1t  = (unsigned short*)carve((size_t)HID * DIN * 2);
    unsigned short* wmt  = (unsigned short*)carve((size_t)L * HID * HID * 2);
    unsigned short* w2t  = (unsigned short*)carve((size_t)NCLS * HID * 2);
    unsigned short* hb   = xb;   // alias: xb consumed by first GEMM before hb written

    // --- CSR build ---
    hipMemsetAsync(deg, 0, (size_t)N * 4, stream);
    hist_kernel<<<(E + 255) / 256, 256, 0, stream>>>(erow, deg, E);
    scan_kernel<<<1, 1024, 0, stream>>>(deg, offs, N);
    hipMemcpyAsync(pos, offs, (size_t)N * 4, hipMemcpyDeviceToDevice, stream);
    fill_kernel<<<(E + 255) / 256, 256, 0, stream>>>(erow, ecol, eval, pos, ccol, cval, E);

    // --- precision prep ---
    f2bf_vec_kernel<<<(N * DIN / 4 + 255) / 256, 256, 0, stream>>>(x, xb, N * DIN / 4);
    wtrans_kernel<<<(DIN * HID + 255) / 256, 256, 0, stream>>>(w1, w1t, DIN, HID);
    for (int i = 0; i < L; ++i)
        wtrans_kernel<<<(HID * HID + 255) / 256, 256, 0, stream>>>(
            wm + (size_t)i * HID * HID, wmt + (size_t)i * HID * HID, HID, HID);
    wtrans_kernel<<<(HID * NCLS + 255) / 256, 256, 0, stream>>>(w2, w2t, HID, NCLS);

    const int spmm_blocks = (N + 3) / 4;
    const int gemm_blocks = N / 64;   // 625 exact

    // --- layer 1 ---
    gemm_mfma_kernel<HID><<<gemm_blocks, 256, 0, stream>>>(xb, w1t, b1, z, DIN);
    spmm_kernel<HID, 0><<<spmm_blocks, 256, 0, stream>>>(offs, ccol, cval, z, h, hb, nullptr, N);

    // --- middle residual layers ---
    for (int i = 0; i < L; ++i) {
        gemm_mfma_kernel<HID><<<gemm_blocks, 256, 0, stream>>>(
            hb, wmt + (size_t)i * HID * HID, bmp + (size_t)i * HID, z, HID);
        spmm_kernel<HID, 1><<<spmm_blocks, 256, 0, stream>>>(offs, ccol, cval, z, h, hb, dt, N);
    }

    // --- output layer ---
    gemm_mfma_kernel<NCLS><<<gemm_blocks, 256, 0, stream>>>(hb, w2t, b2, z, HID);
    spmm_kernel<NCLS, 2><<<spmm_blocks, 256, 0, stream>>>(offs, ccol, cval, z, outp, nullptr, nullptr, N);
}

// Round 4
// 299.431 us; speedup vs baseline: 2.0237x; 1.2120x over previous
//
#include <hip/hip_runtime.h>

// DeepGCN forward on MI355X.
// R3 post-mortem: fill_kernel was #1 (46us, WRITE 68MB vs 5.1MB useful =
// cross-XCD line-writeback amplification on 2x4B scattered stores).
// R4: (a) interleaved int2 (col,val) -> 1 store/edge, halves touched lines;
// (b) fill co-scheduled with GEMM1 (store-bound || MFMA-bound) in one kernel,
// GEMM1 converts x fp32->bf16 inline (kills f2bf pass); (c) 2-kernel scan,
// scan writes pos directly (kills memcpy); one wtrans kernel.

#define DIN 256
#define HID 128
#define NCLS 64

typedef __attribute__((ext_vector_type(8))) short bf16x8;   // 8 bf16 = 4 VGPRs
typedef __attribute__((ext_vector_type(4))) float f32x4;

static __device__ __forceinline__ float bf2f(unsigned int u) {
    return __uint_as_float(u << 16);
}
static __device__ __forceinline__ unsigned short f2bf(float f) {
    unsigned int i = __float_as_uint(f);
    unsigned int r = (i + 0x7FFFu + ((i >> 16) & 1u)) >> 16;   // RNE
    return (unsigned short)r;
}
static __device__ __forceinline__ unsigned int pack2(float a, float b) {
    return (unsigned int)f2bf(a) | ((unsigned int)f2bf(b) << 16);
}

// ---------------- CSR build ----------------

__global__ void hist_kernel(const int* __restrict__ row, int* __restrict__ deg, int E) {
    int e = blockIdx.x * blockDim.x + threadIdx.x;
    if (e < E) atomicAdd(&deg[row[e]], 1);
}

// Hierarchical scan, tile = 1024. k1: per-tile sums.
__global__ __launch_bounds__(1024) void scan_sums_kernel(
        const int* __restrict__ deg, int* __restrict__ bsums, int n) {
    __shared__ int wsum[16];
    const int lane = threadIdx.x & 63;
    const int wid  = threadIdx.x >> 6;
    int i = blockIdx.x * 1024 + threadIdx.x;
    int v = (i < n) ? deg[i] : 0;
    #pragma unroll
    for (int d = 32; d >= 1; d >>= 1) v += __shfl_xor(v, d, 64);
    if (lane == 0) wsum[wid] = v;
    __syncthreads();
    if (threadIdx.x == 0) {
        int s = 0;
        #pragma unroll
        for (int w = 0; w < 16; ++w) s += wsum[w];
        bsums[blockIdx.x] = s;
    }
}

// k2: each block recomputes its tile's exclusive scan + block prefix from
// bsums (nb <= 64 so one wave handles it); writes offs AND pos.
__global__ __launch_bounds__(1024) void scan_fix_kernel(
        const int* __restrict__ deg, const int* __restrict__ bsums,
        int* __restrict__ offs, int* __restrict__ pos, int n, int nb) {
    __shared__ int wsum[16];
    __shared__ int bpref_s;
    const int lane = threadIdx.x & 63;
    const int wid  = threadIdx.x >> 6;
    const int b = blockIdx.x;
    if (wid == 0) {
        int v = (lane < nb && lane < b) ? bsums[lane] : 0;
        #pragma unroll
        for (int d = 32; d >= 1; d >>= 1) v += __shfl_xor(v, d, 64);
        if (lane == 0) bpref_s = v;
    }
    int i = b * 1024 + (int)threadIdx.x;
    int v = (i < n) ? deg[i] : 0;
    int incl = v;
    #pragma unroll
    for (int d = 1; d < 64; d <<= 1) {
        int t = __shfl_up(incl, d, 64);
        if (lane >= d) incl += t;
    }
    if (lane == 63) wsum[wid] = incl;
    __syncthreads();
    int wpref = 0;
    #pragma unroll
    for (int w = 0; w < 16; ++w)
        if (w < wid) wpref += wsum[w];
    int excl = bpref_s + wpref + incl - v;
    if (i < n) { offs[i] = excl; pos[i] = excl; }
    if (i == n) offs[n] = excl;
}

// ---------------- weight prep: all transposes+converts in one kernel ----------------
// w1t[n*256+k]=w1[k*128+n]; wmt[i][n*128+k]=wm[i][k*128+n]; w2t[n*128+k]=w2[k*64+n]
__global__ void wtrans_all_kernel(const float* __restrict__ w1, const float* __restrict__ wm,
                                  const float* __restrict__ w2,
                                  unsigned short* __restrict__ w1t, unsigned short* __restrict__ wmt,
                                  unsigned short* __restrict__ w2t, int L) {
    int idx = blockIdx.x * blockDim.x + threadIdx.x;
    int n1 = DIN * HID;
    int n2 = n1 + L * HID * HID;
    int n3 = n2 + HID * NCLS;
    if (idx < n1) {
        int n = idx / DIN, k = idx - n * DIN;
        w1t[idx] = f2bf(w1[(size_t)k * HID + n]);
    } else if (idx < n2) {
        int j = idx - n1;
        int i = j / (HID * HID), r = j - i * (HID * HID);
        int n = r / HID, k = r - n * HID;
        wmt[j] = f2bf(wm[(size_t)i * HID * HID + (size_t)k * HID + n]);
    } else if (idx < n3) {
        int j = idx - n2;
        int n = j / HID, k = j - n * HID;
        w2t[j] = f2bf(w2[(size_t)k * NCLS + n]);
    }
}

// ---------------- MEGA1: GEMM1 (x fp32 -> bf16 inline, K=256, BN=128) || CSR fill ----------------
__global__ __launch_bounds__(256) void mega1_kernel(
        const float* __restrict__ x, const unsigned short* __restrict__ w1t,
        const float* __restrict__ b1, unsigned short* __restrict__ z,
        const int* __restrict__ erow, const int* __restrict__ ecol,
        const float* __restrict__ eval, int* __restrict__ pos,
        int2* __restrict__ edges, int E, int gemmBlocks) {
    const int tid = threadIdx.x;
    if ((int)blockIdx.x >= gemmBlocks) {
        // ---- CSR fill: one int2 store per edge ----
        int nfb = gridDim.x - gemmBlocks;
        for (int e = (blockIdx.x - gemmBlocks) * 256 + tid; e < E; e += nfb * 256) {
            int r = erow[e];
            int p = atomicAdd(&pos[r], 1);
            int2 o;
            o.x = ecol[e];
            o.y = __float_as_int(eval[e]);
            edges[p] = o;
        }
        return;
    }
    // ---- GEMM1 tile: 64 x 128, K=256 ----
    __shared__ __align__(16) unsigned short Alds[64 * 40];
    __shared__ __align__(16) unsigned short Blds[128 * 40];
    const int bm   = blockIdx.x * 64;
    const int wave = tid >> 6;
    const int lane = tid & 63;
    const int m16  = lane & 15;
    const int quad = lane >> 4;
    const int ar = tid >> 2, ac = (tid & 3) * 8;

    f32x4 acc[8] = {};
    for (int k0 = 0; k0 < DIN; k0 += 32) {
        float4 a0 = *(const float4*)&x[(size_t)(bm + ar) * DIN + k0 + ac];
        float4 a1 = *(const float4*)&x[(size_t)(bm + ar) * DIN + k0 + ac + 4];
        uint4 av;
        av.x = pack2(a0.x, a0.y); av.y = pack2(a0.z, a0.w);
        av.z = pack2(a1.x, a1.y); av.w = pack2(a1.z, a1.w);
        *(uint4*)&Alds[ar * 40 + ac] = av;
        #pragma unroll
        for (int i = 0; i < 2; ++i) {
            int c  = tid + 256 * i;
            int br = c >> 2, bc = (c & 3) * 8;
            *(uint4*)&Blds[br * 40 + bc] = *(const uint4*)&w1t[(size_t)br * DIN + k0 + bc];
        }
        __syncthreads();
        bf16x8 af = *(const bf16x8*)&Alds[(wave * 16 + m16) * 40 + quad * 8];
        #pragma unroll
        for (int j = 0; j < 8; ++j) {
            bf16x8 bf = *(const bf16x8*)&Blds[(j * 16 + m16) * 40 + quad * 8];
            acc[j] = __builtin_amdgcn_mfma_f32_16x16x32_bf16(af, bf, acc[j], 0, 0, 0);
        }
        __syncthreads();
    }
    #pragma unroll
    for (int j = 0; j < 8; ++j) {
        int col = j * 16 + m16;
        float bb = b1[col];
        #pragma unroll
        for (int r = 0; r < 4; ++r) {
            int row = bm + wave * 16 + quad * 4 + r;
            z[(size_t)row * HID + col] = f2bf(acc[j][r] + bb);
        }
    }
}

// ---------------- MFMA bf16 GEMM (A already bf16): C[N,BN]=A@Wt^T+bias ----------------
template <int BN>
__global__ __launch_bounds__(256) void gemm_mfma_kernel(
        const unsigned short* __restrict__ A, const unsigned short* __restrict__ Wt,
        const float* __restrict__ bias, unsigned short* __restrict__ C, int K) {
    constexpr int NT = BN / 16;
    __shared__ __align__(16) unsigned short Alds[64 * 40];
    __shared__ __align__(16) unsigned short Blds[BN * 40];
    const int tid  = threadIdx.x;
    const int bm   = blockIdx.x * 64;
    const int wave = tid >> 6;
    const int lane = tid & 63;
    const int m16  = lane & 15;
    const int quad = lane >> 4;
    const int ar = tid >> 2, ac = (tid & 3) * 8;

    f32x4 acc[NT] = {};
    for (int k0 = 0; k0 < K; k0 += 32) {
        uint4 av = *(const uint4*)&A[(size_t)(bm + ar) * K + k0 + ac];
        *(uint4*)&Alds[ar * 40 + ac] = av;
        #pragma unroll
        for (int i = 0; i < BN / 64; ++i) {
            int c  = tid + 256 * i;
            int br = c >> 2, bc = (c & 3) * 8;
            *(uint4*)&Blds[br * 40 + bc] = *(const uint4*)&Wt[(size_t)br * K + k0 + bc];
        }
        __syncthreads();
        bf16x8 af = *(const bf16x8*)&Alds[(wave * 16 + m16) * 40 + quad * 8];
        #pragma unroll
        for (int j = 0; j < NT; ++j) {
            bf16x8 bf = *(const bf16x8*)&Blds[(j * 16 + m16) * 40 + quad * 8];
            acc[j] = __builtin_amdgcn_mfma_f32_16x16x32_bf16(af, bf, acc[j], 0, 0, 0);
        }
        __syncthreads();
    }
    #pragma unroll
    for (int j = 0; j < NT; ++j) {
        int col = j * 16 + m16;
        float bb = bias[col];
        #pragma unroll
        for (int r = 0; r < 4; ++r) {
            int row = bm + wave * 16 + quad * 4 + r;
            C[(size_t)row * BN + col] = f2bf(acc[j][r] + bb);
        }
    }
}

// ---------------- SpMM over bf16 z, int2 edges, fp32 accumulate ----------------
// MODE 0: h = relu(s); hb = bf16(h)   MODE 1: h += relu(s)*dt; hb = bf16(h)
// MODE 2: out = s (fp32)
template <int D, int MODE>
__global__ __launch_bounds__(256) void spmm_kernel(
        const int* __restrict__ offs, const int2* __restrict__ edges,
        const unsigned short* __restrict__ z,
        float* __restrict__ out, unsigned short* __restrict__ hb,
        const float* __restrict__ dt_ptr, int n) {
    int r = (int)((blockIdx.x * blockDim.x + threadIdx.x) >> 6);
    int lane = threadIdx.x & 63;
    if (r >= n) return;
    r = __builtin_amdgcn_readfirstlane(r);
    const int s = offs[r], e = offs[r + 1];
    float acc0 = 0.f, acc1 = 0.f;
    int p = s;
    if (D == 128) {
        const unsigned int* z32 = (const unsigned int*)z;
        for (; p + 4 <= e; p += 4) {
            int2 e0 = edges[p], e1 = edges[p + 1], e2 = edges[p + 2], e3 = edges[p + 3];
            unsigned int g0 = z32[(size_t)e0.x * 64 + lane];
            unsigned int g1 = z32[(size_t)e1.x * 64 + lane];
            unsigned int g2 = z32[(size_t)e2.x * 64 + lane];
            unsigned int g3 = z32[(size_t)e3.x * 64 + lane];
            float v0 = __int_as_float(e0.y), v1 = __int_as_float(e1.y);
            float v2 = __int_as_float(e2.y), v3 = __int_as_float(e3.y);
            acc0 = fmaf(v0, bf2f(g0 & 0xffffu), acc0); acc1 = fmaf(v0, bf2f(g0 >> 16), acc1);
            acc0 = fmaf(v1, bf2f(g1 & 0xffffu), acc0); acc1 = fmaf(v1, bf2f(g1 >> 16), acc1);
            acc0 = fmaf(v2, bf2f(g2 & 0xffffu), acc0); acc1 = fmaf(v2, bf2f(g2 >> 16), acc1);
            acc0 = fmaf(v3, bf2f(g3 & 0xffffu), acc0); acc1 = fmaf(v3, bf2f(g3 >> 16), acc1);
        }
        for (; p < e; ++p) {
            int2 ed = edges[p];
            float v = __int_as_float(ed.y);
            unsigned int g = z32[(size_t)ed.x * 64 + lane];
            acc0 = fmaf(v, bf2f(g & 0xffffu), acc0); acc1 = fmaf(v, bf2f(g >> 16), acc1);
        }
        float2* op = (float2*)&out[(size_t)r * 128 + 2 * lane];
        float f0, f1;
        if (MODE == 0) {
            f0 = fmaxf(acc0, 0.f); f1 = fmaxf(acc1, 0.f);
            float2 o; o.x = f0; o.y = f1; *op = o;
        } else if (MODE == 1) {
            float dt = *dt_ptr;
            float2 cur = *op;
            f0 = cur.x + fmaxf(acc0, 0.f) * dt;
            f1 = cur.y + fmaxf(acc1, 0.f) * dt;
            float2 o; o.x = f0; o.y = f1; *op = o;
        } else {
            float2 o; o.x = acc0; o.y = acc1; *op = o;
            return;
        }
        ((unsigned int*)hb)[(size_t)r * 64 + lane] = pack2(f0, f1);
    } else {  // D == 64 (final layer, MODE 2)
        for (; p + 4 <= e; p += 4) {
            int2 e0 = edges[p], e1 = edges[p + 1], e2 = edges[p + 2], e3 = edges[p + 3];
            unsigned int g0 = z[(size_t)e0.x * 64 + lane];
            unsigned int g1 = z[(size_t)e1.x * 64 + lane];
            unsigned int g2 = z[(size_t)e2.x * 64 + lane];
            unsigned int g3 = z[(size_t)e3.x * 64 + lane];
            acc0 = fmaf(__int_as_float(e0.y), bf2f(g0), acc0);
            acc0 = fmaf(__int_as_float(e1.y), bf2f(g1), acc0);
            acc0 = fmaf(__int_as_float(e2.y), bf2f(g2), acc0);
            acc0 = fmaf(__int_as_float(e3.y), bf2f(g3), acc0);
        }
        for (; p < e; ++p) {
            int2 ed = edges[p];
            acc0 = fmaf(__int_as_float(ed.y), bf2f((unsigned int)z[(size_t)ed.x * 64 + lane]), acc0);
        }
        out[(size_t)r * 64 + lane] = acc0;
    }
}

extern "C" void kernel_launch(void* const* d_in, const int* in_sizes, int n_in,
                              void* d_out, int out_size, void* d_ws, size_t ws_size,
                              hipStream_t stream) {
    const float* x    = (const float*)d_in[0];
    const int*   erow = (const int*)d_in[1];
    const int*   ecol = (const int*)d_in[2];
    const float* eval = (const float*)d_in[3];
    const float* w1   = (const float*)d_in[4];
    const float* b1   = (const float*)d_in[5];
    const float* wm   = (const float*)d_in[6];
    const float* bmp  = (const float*)d_in[7];
    const float* w2   = (const float*)d_in[8];
    const float* b2   = (const float*)d_in[9];
    const float* dt   = (const float*)d_in[10];

    const int N = in_sizes[0] / DIN;       // 40000
    const int E = in_sizes[1];             // 640000
    const int L = in_sizes[7] / HID;       // 2

    float* outp = (float*)d_out;

    char* ws = (char*)d_ws;
    auto carve = [&](size_t bytes) -> char* {
        char* p = ws;
        ws += (bytes + 255) & ~(size_t)255;
        return p;
    };
    int*            deg   = (int*)carve((size_t)N * 4);
    int*            bsums = (int*)carve(64 * 4);
    int*            offs  = (int*)carve((size_t)(N + 1) * 4);
    int*            pos   = (int*)carve((size_t)N * 4);
    int2*           edges = (int2*)carve((size_t)E * 8);
    unsigned short* z     = (unsigned short*)carve((size_t)N * HID * 2);
    float*          h     = (float*)carve((size_t)N * HID * 4);
    unsigned short* hb    = (unsigned short*)carve((size_t)N * HID * 2);
    unsigned short* w1t   = (unsigned short*)carve((size_t)HID * DIN * 2);
    unsigned short* wmt   = (unsigned short*)carve((size_t)L * HID * HID * 2);
    unsigned short* w2t   = (unsigned short*)carve((size_t)NCLS * HID * 2);

    const int ntiles = (N + 1024) / 1024;  // covers i == n
    const int wtotal = DIN * HID + L * HID * HID + HID * NCLS;

    // --- independent prep ---
    wtrans_all_kernel<<<(wtotal + 255) / 256, 256, 0, stream>>>(w1, wm, w2, w1t, wmt, w2t, L);
    hipMemsetAsync(deg, 0, (size_t)N * 4, stream);
    hist_kernel<<<(E + 255) / 256, 256, 0, stream>>>(erow, deg, E);
    scan_sums_kernel<<<ntiles, 1024, 0, stream>>>(deg, bsums, N);
    scan_fix_kernel<<<ntiles, 1024, 0, stream>>>(deg, bsums, offs, pos, N, ntiles);

    const int gemm_blocks = N / 64;   // 625 exact
    const int spmm_blocks = (N + 3) / 4;

    // --- GEMM1 || CSR-fill ---
    mega1_kernel<<<gemm_blocks * 2, 256, 0, stream>>>(
        x, w1t, b1, z, erow, ecol, eval, pos, edges, E, gemm_blocks);
    spmm_kernel<HID, 0><<<spmm_blocks, 256, 0, stream>>>(offs, edges, z, h, hb, nullptr, N);

    // --- middle residual layers ---
    for (int i = 0; i < L; ++i) {
        gemm_mfma_kernel<HID><<<gemm_blocks, 256, 0, stream>>>(
            hb, wmt + (size_t)i * HID * HID, bmp + (size_t)i * HID, z, HID);
        spmm_kernel<HID, 1><<<spmm_blocks, 256, 0, stream>>>(offs, edges, z, h, hb, dt, N);
    }

    // --- output layer ---
    gemm_mfma_kernel<NCLS><<<gemm_blocks, 256, 0, stream>>>(hb, w2t, b2, z, HID);
    spmm_kernel<NCLS, 2><<<spmm_blocks, 256, 0, stream>>>(offs, edges, z, outp, nullptr, nullptr, N);
}